// Round 15
// baseline (3036.884 us; speedup 1.0000x reference)
//
#include <hip/hip_runtime.h>

typedef _Float16 h2_t __attribute__((ext_vector_type(2)));
typedef _Float16 h4_t __attribute__((ext_vector_type(4)));
typedef _Float16 h8_t __attribute__((ext_vector_type(8)));
typedef float    f4_t __attribute__((ext_vector_type(4)));
typedef unsigned short u16;

#define EMB   512
#define VOCAB 256
#define NB    64
#define NT    1024

// tanh(z) = 1 - 2/(e^{2z}+1) with raw v_rcp_f32 (R8 win: -8%, VALU 0.76->0.49)
__device__ __forceinline__ float fast_tanh(float z) {
    float e = __expf(2.0f * z);
    float r = __builtin_amdgcn_rcpf(e + 1.0f);
    return fmaf(-2.0f, r, 1.0f);
}

__device__ __forceinline__ unsigned pk2(float a, float b) {
    return __builtin_bit_cast(unsigned, __builtin_amdgcn_cvt_pkrtz(a, b));
}

// ---------------------------------------------------------------------------
// Prep: emb_proj = emb @ w_x^T + b_cell (-> f16), pack w_h -> f16, w_head -> f16
// ---------------------------------------------------------------------------
__global__ __launch_bounds__(256) void prep_kernel(
    const float* __restrict__ emb, const float* __restrict__ w_cell,
    const float* __restrict__ b_cell, const float* __restrict__ w_head,
    u16* __restrict__ embp, unsigned* __restrict__ W2, u16* __restrict__ wh16)
{
    const int blk = blockIdx.x, tid = threadIdx.x;
    if (blk < 256) {
        const int v = blk;
        __shared__ __align__(16) float er[EMB];
        er[tid]       = emb[v * EMB + tid];
        er[tid + 256] = emb[v * EMB + 256 + tid];
        __syncthreads();
        const f4_t* er4 = (const f4_t*)er;
        #pragma unroll
        for (int half = 0; half < 2; ++half) {
            const int o = tid + half * 256;
            const f4_t* wr4 = (const f4_t*)(w_cell + (size_t)o * 1024); // w_x row o
            float s0 = 0.f, s1 = 0.f, s2 = 0.f, s3 = 0.f;
            #pragma unroll 8
            for (int e4 = 0; e4 < 128; ++e4) {
                f4_t w = wr4[e4], a = er4[e4];
                s0 = fmaf(w[0], a[0], s0);
                s1 = fmaf(w[1], a[1], s1);
                s2 = fmaf(w[2], a[2], s2);
                s3 = fmaf(w[3], a[3], s3);
            }
            const float r = (s0 + s1) + (s2 + s3) + b_cell[o];
            embp[v * EMB + o] = __builtin_bit_cast(u16, (_Float16)r);   // f16 store
        }
    } else if (blk < 384) {
        // pack w_h[o][e] (= w_cell[o*1024 + 512 + e]) into f16: W2 as u16[o*512+e]
        const int base = (blk - 256) * 1024 + tid;
        #pragma unroll
        for (int i = 0; i < 4; ++i) {
            const int P = base + i * 256;          // 0..131071 (pairs)
            const int o = P >> 8, p = P & 255;
            h2_t v2;
            v2[0] = (_Float16)w_cell[(size_t)o * 1024 + 512 + 2 * p];
            v2[1] = (_Float16)w_cell[(size_t)o * 1024 + 512 + 2 * p + 1];
            W2[P] = __builtin_bit_cast(unsigned, v2);
        }
    } else {
        const int base = (blk - 384) * 2048 + tid;
        #pragma unroll
        for (int i = 0; i < 8; ++i) {
            const int idx = base + i * 256;        // 0..131071
            wh16[idx] = __builtin_bit_cast(u16, (_Float16)w_head[idx]);
        }
    }
}

// ---------------------------------------------------------------------------
// Recurrence, transposed MFMA: h_new^T[512 x 16] = w_h x h^T per step.
// Best structure (R12: 2541 us): 4 blocks x 512 threads, 12 AGPR k-slabs +
// 4 in-loop LDS k-slabs, f16 xw dbuf, token-2-ahead, bf/al register
// windows, cheap tanh (rcp), acc-pair phase split, LDS-only barrier.
// R14's ONE knob: t-loop UNROLLED BY 2 with compile-time-static buffer
// parities — kills the per-iteration (t&1) hbuf base recompute and lets
// the compiler rename away the loop-carried xw_cur=xw_next copies.
// No new live state across barriers; bit-identical numerics.
// LDS = 128 + 32 = 160 KB. NO setprio (R13: 3.6x regression).
// ---------------------------------------------------------------------------
__global__ __launch_bounds__(512, 2) void rnn_rec(
    const int* __restrict__ x, const float* __restrict__ h0,
    const u16* __restrict__ whf, const u16* __restrict__ embf,
    u16* __restrict__ hs)
{
    extern __shared__ __align__(16) u16 smem[];
    u16* wlds = smem;            // 65536 u16 = 128 KB: frag f=(sp*32+I)*64+lane
    u16* hbuf = smem + 65536;    // [2][8192] u16 = 32 KB, B-frag order

    const int tid  = threadIdx.x;
    const int wave = tid >> 6, lane = tid & 63;
    const int n    = lane & 15, quad = lane >> 4;   // n = batch-in-block
    const int b0   = blockIdx.x * 16;

    // ---- stage w_h k-slabs 12..15 into LDS (one-time, constant) ----
    #pragma unroll
    for (int g = 0; g < 16; ++g) {
        const int f = g * 512 + tid;                // frag id 0..8191
        const int lf = f & 63, If = (f >> 6) & 31, sp = f >> 11;
        const int m = If * 16 + (lf & 15);
        const int k = 384 + sp * 32 + (lf >> 4) * 8;
        *(uint4*)&wlds[(size_t)f * 8] = *(const uint4*)&whf[(size_t)m * 512 + k];
    }

    {   // h0 -> buffer 0, all 16 batch columns (B-frag order)
        const u16 u = __builtin_bit_cast(u16, (_Float16)h0[tid]);
        const int e = tid;
        const int ob = ((e >> 5) * 64 + ((e >> 3) & 3) * 16) * 8 + (e & 7);
        #pragma unroll
        for (int nn = 0; nn < 16; ++nn) hbuf[ob + nn * 8] = u;
    }

    // ---- resident A fragments: rows m = (wave*4+i)*16+n, k-slabs 0..11 ----
    h8_t Af[4][12];
    #pragma unroll
    for (int i = 0; i < 4; ++i)
        #pragma unroll
        for (int s = 0; s < 12; ++s)
            Af[i][s] = *(const h8_t*)&whf[(size_t)(((wave << 2) + i) * 16 + n) * EMB
                                          + s * 32 + quad * 8];

    const int* xp  = x  + (size_t)(b0 + n) * NT;
    u16*       hsp = hs + (size_t)(b0 + n) * NT * EMB;

    int eofs[4], wofs[4];
    #pragma unroll
    for (int i = 0; i < 4; ++i) {
        const int I = (wave << 2) + i;
        eofs[i] = I * 16 + (quad << 2);                       // e-offset of acc[i]
        const int qq = (2 * I + (quad >> 1)) & 3;
        wofs[i] = ((I >> 1) * 64 + qq * 16 + n) * 8 + (quad & 1) * 4;
    }

    __syncthreads();

    int vB = xp[0];
    h4_t xw_cur[4];                                           // f16 xw (2 regs each)
    #pragma unroll
    for (int i = 0; i < 4; ++i)
        xw_cur[i] = *(const h4_t*)&embf[(size_t)vB * EMB + eofs[i]];
    vB = xp[1];

    // one recurrence step with compile-time-static src/dst buffers
    auto step = [&](const u16* __restrict__ hb, u16* __restrict__ hw, int t) {
        const int vC = xp[(t + 2 < NT) ? t + 2 : NT - 1];     // token t+2 (clamped)
        h4_t xw_next[4];                                      // xw for t+1, in flight
        #pragma unroll
        for (int i = 0; i < 4; ++i)
            xw_next[i] = *(const h4_t*)&embf[(size_t)vB * EMB + eofs[i]];

        // ---- register windows: issue ALL step-t ds_reads up front ----
        h8_t bf[16];                                          // 64 VGPR
        #pragma unroll
        for (int s = 0; s < 16; ++s)
            bf[s] = *(const h8_t*)&hb[s * 512 + lane * 8];
        h8_t al[4][4];                                        // 64 VGPR
        #pragma unroll
        for (int sp = 0; sp < 4; ++sp)
            #pragma unroll
            for (int i = 0; i < 4; ++i)
                al[sp][i] = *(const h8_t*)
                    &wlds[((sp * 32 + (wave << 2) + i) * 64 + lane) * 8];

        f4_t acc[4];
        #pragma unroll
        for (int i = 0; i < 4; ++i) {                         // xw as C-init (cvt)
            acc[i][0] = (float)xw_cur[i][0];
            acc[i][1] = (float)xw_cur[i][1];
            acc[i][2] = (float)xw_cur[i][2];
            acc[i][3] = (float)xw_cur[i][3];
        }

        // ================= PAIR 0: acc[0], acc[1] =================
        #pragma unroll
        for (int s = 0; s < 12; ++s) {
            acc[0] = __builtin_amdgcn_mfma_f32_16x16x32_f16(Af[0][s], bf[s],
                                                            acc[0], 0, 0, 0);
            acc[1] = __builtin_amdgcn_mfma_f32_16x16x32_f16(Af[1][s], bf[s],
                                                            acc[1], 0, 0, 0);
        }
        #pragma unroll
        for (int sp = 0; sp < 4; ++sp) {
            acc[0] = __builtin_amdgcn_mfma_f32_16x16x32_f16(al[sp][0], bf[12 + sp],
                                                            acc[0], 0, 0, 0);
            acc[1] = __builtin_amdgcn_mfma_f32_16x16x32_f16(al[sp][1], bf[12 + sp],
                                                            acc[1], 0, 0, 0);
        }
        // pair-0 tail: tanh + LDS + global write (overlaps pair-1 MFMAs below)
        #pragma unroll
        for (int i = 0; i < 2; ++i) {
            const f4_t a = acc[i];
            uint2 pk;
            pk.x = pk2(fast_tanh(a[0]), fast_tanh(a[1]));
            pk.y = pk2(fast_tanh(a[2]), fast_tanh(a[3]));
            *(uint2*)&hw[wofs[i]] = pk;                       // LDS, B-frag order
            *(uint2*)&hsp[(size_t)t * EMB + eofs[i]] = pk;    // global, no drain
        }

        // ================= PAIR 1: acc[2], acc[3] =================
        #pragma unroll
        for (int s = 0; s < 12; ++s) {
            acc[2] = __builtin_amdgcn_mfma_f32_16x16x32_f16(Af[2][s], bf[s],
                                                            acc[2], 0, 0, 0);
            acc[3] = __builtin_amdgcn_mfma_f32_16x16x32_f16(Af[3][s], bf[s],
                                                            acc[3], 0, 0, 0);
        }
        #pragma unroll
        for (int sp = 0; sp < 4; ++sp) {
            acc[2] = __builtin_amdgcn_mfma_f32_16x16x32_f16(al[sp][2], bf[12 + sp],
                                                            acc[2], 0, 0, 0);
            acc[3] = __builtin_amdgcn_mfma_f32_16x16x32_f16(al[sp][3], bf[12 + sp],
                                                            acc[3], 0, 0, 0);
        }
        #pragma unroll
        for (int i = 2; i < 4; ++i) {
            const f4_t a = acc[i];
            uint2 pk;
            pk.x = pk2(fast_tanh(a[0]), fast_tanh(a[1]));
            pk.y = pk2(fast_tanh(a[2]), fast_tanh(a[3]));
            *(uint2*)&hw[wofs[i]] = pk;                       // LDS, B-frag order
            *(uint2*)&hsp[(size_t)t * EMB + eofs[i]] = pk;    // global, no drain
        }

        vB = vC;
        #pragma unroll
        for (int i = 0; i < 4; ++i) xw_cur[i] = xw_next[i];
    };

    #pragma unroll 1
    for (int t = 0; t < NT; t += 2) {
        step(hbuf, hbuf + 8192, t);                           // even: buf0 -> buf1
        asm volatile("s_waitcnt lgkmcnt(0)\n\ts_barrier" ::: "memory");
        step(hbuf + 8192, hbuf, t + 1);                       // odd:  buf1 -> buf0
        asm volatile("s_waitcnt lgkmcnt(0)\n\ts_barrier" ::: "memory");
    }
}

// ---------------------------------------------------------------------------
// Head: out[bt][n] = hs[bt][:] @ w_head[n][:]^T + b_head[n], MFMA f16 16x16x32.
// ---------------------------------------------------------------------------
__global__ __launch_bounds__(512, 2) void head_kernel(
    const u16* __restrict__ hs, const u16* __restrict__ wh16,
    const float* __restrict__ b_head, float* __restrict__ out)
{
    const int tid  = threadIdx.x;
    const int wave = tid >> 6, lane = tid & 63;
    const int l15  = lane & 15, q = lane >> 4;
    const int bt0  = blockIdx.x * 64;

    __shared__ __align__(16) u16 As[64][520];   // +8 halfs pad: breaks bank aliasing

    {   // stage 64x512 f16 tile
        const uint4* src = (const uint4*)(hs + (size_t)bt0 * EMB);
        #pragma unroll
        for (int i = 0; i < 8; ++i) {
            const int idx = tid + i * 512;       // 0..4095 uint4s
            const int row = idx >> 6, col8 = idx & 63;
            *(uint4*)&As[row][col8 * 8] = src[idx];
        }
    }

    // B fragments: wave owns n-tiles {2*wave, 2*wave+1}; B[k][n] = w_head[n][k]
    uint4 bn[16][2];
    #pragma unroll
    for (int i = 0; i < 16; ++i)
        #pragma unroll
        for (int j = 0; j < 2; ++j) {
            const int n = wave * 32 + j * 16 + l15;
            const int k = i * 32 + q * 8;
            bn[i][j] = *(const uint4*)(wh16 + (size_t)n * EMB + k);
        }
    __syncthreads();

    #pragma unroll 1
    for (int mt = 0; mt < 4; ++mt) {
        f4_t acc0 = {0.f, 0.f, 0.f, 0.f}, acc1 = {0.f, 0.f, 0.f, 0.f};
        const int row = mt * 16 + l15;
        #pragma unroll
        for (int i = 0; i < 16; ++i) {
            const int k = i * 32 + q * 8;
            h8_t a = *(const h8_t*)&As[row][k];
            acc0 = __builtin_amdgcn_mfma_f32_16x16x32_f16(
                a, __builtin_bit_cast(h8_t, bn[i][0]), acc0, 0, 0, 0);
            acc1 = __builtin_amdgcn_mfma_f32_16x16x32_f16(
                a, __builtin_bit_cast(h8_t, bn[i][1]), acc1, 0, 0, 0);
        }
        #pragma unroll
        for (int j = 0; j < 2; ++j) {
            const int n = wave * 32 + j * 16 + l15;
            const float bh = b_head[n];
            const f4_t av = j ? acc1 : acc0;
            #pragma unroll
            for (int r = 0; r < 4; ++r) {
                const int orow = bt0 + mt * 16 + q * 4 + r;   // D: row=q*4+r, col=l15
                out[(size_t)orow * VOCAB + n] = av[r] + bh;
            }
        }
    }
}

extern "C" void kernel_launch(void* const* d_in, const int* in_sizes, int n_in,
                              void* d_out, int out_size, void* d_ws, size_t ws_size,
                              hipStream_t stream) {
    (void)in_sizes; (void)n_in; (void)out_size; (void)ws_size;
    const int*   x      = (const int*)  d_in[0];
    const float* emb    = (const float*)d_in[1];
    const float* w_cell = (const float*)d_in[2];
    const float* b_cell = (const float*)d_in[3];
    const float* w_head = (const float*)d_in[4];
    const float* b_head = (const float*)d_in[5];
    const float* h0     = (const float*)d_in[6];
    float* out = (float*)d_out;

    char* ws = (char*)d_ws;
    u16*      embf = (u16*)     (ws);                 // 256*512*2 = 256 KB (f16)
    unsigned* W2   = (unsigned*)(ws + 524288);        // 512*256*4 = 512 KB (f16 w_h)
    u16*      wh16 = (u16*)     (ws + 1048576);       // 256*512*2 = 256 KB
    u16*      hs   = (u16*)     (ws + 1310720);       // 64*1024*512*2 = 64 MB

    // allow 160 KB dynamic LDS (idempotent; same every call -> graph-safe)
    hipFuncSetAttribute((const void*)rnn_rec,
                        hipFuncAttributeMaxDynamicSharedMemorySize, 163840);

    prep_kernel<<<dim3(448), dim3(256), 0, stream>>>(emb, w_cell, b_cell, w_head,
                                                     embf, W2, wh16);
    rnn_rec<<<dim3(4), dim3(512), 163840, stream>>>(x, h0, (const u16*)W2, embf, hs);
    head_kernel<<<dim3((NB * NT) / 64), dim3(512), 0, stream>>>(hs, wh16, b_head, out);
}

// Round 16
// 2695.227 us; speedup vs baseline: 1.1268x; 1.1268x over previous
//
#include <hip/hip_runtime.h>

typedef _Float16 h2_t __attribute__((ext_vector_type(2)));
typedef _Float16 h4_t __attribute__((ext_vector_type(4)));
typedef _Float16 h8_t __attribute__((ext_vector_type(8)));
typedef float    f4_t __attribute__((ext_vector_type(4)));
typedef unsigned short u16;

#define EMB   512
#define VOCAB 256
#define NB    64
#define NT    1024

// tanh(z) = 1 - 2/(e^{2z}+1) with raw v_rcp_f32 (R8 win: -8%, VALU 0.76->0.49)
__device__ __forceinline__ float fast_tanh(float z) {
    float e = __expf(2.0f * z);
    float r = __builtin_amdgcn_rcpf(e + 1.0f);
    return fmaf(-2.0f, r, 1.0f);
}

__device__ __forceinline__ unsigned pk2(float a, float b) {
    return __builtin_bit_cast(unsigned, __builtin_amdgcn_cvt_pkrtz(a, b));
}

// ---------------------------------------------------------------------------
// Prep: emb_proj = emb @ w_x^T + b_cell (-> f16), pack w_h -> f16, w_head -> f16
// ---------------------------------------------------------------------------
__global__ __launch_bounds__(256) void prep_kernel(
    const float* __restrict__ emb, const float* __restrict__ w_cell,
    const float* __restrict__ b_cell, const float* __restrict__ w_head,
    u16* __restrict__ embp, unsigned* __restrict__ W2, u16* __restrict__ wh16)
{
    const int blk = blockIdx.x, tid = threadIdx.x;
    if (blk < 256) {
        const int v = blk;
        __shared__ __align__(16) float er[EMB];
        er[tid]       = emb[v * EMB + tid];
        er[tid + 256] = emb[v * EMB + 256 + tid];
        __syncthreads();
        const f4_t* er4 = (const f4_t*)er;
        #pragma unroll
        for (int half = 0; half < 2; ++half) {
            const int o = tid + half * 256;
            const f4_t* wr4 = (const f4_t*)(w_cell + (size_t)o * 1024); // w_x row o
            float s0 = 0.f, s1 = 0.f, s2 = 0.f, s3 = 0.f;
            #pragma unroll 8
            for (int e4 = 0; e4 < 128; ++e4) {
                f4_t w = wr4[e4], a = er4[e4];
                s0 = fmaf(w[0], a[0], s0);
                s1 = fmaf(w[1], a[1], s1);
                s2 = fmaf(w[2], a[2], s2);
                s3 = fmaf(w[3], a[3], s3);
            }
            const float r = (s0 + s1) + (s2 + s3) + b_cell[o];
            embp[v * EMB + o] = __builtin_bit_cast(u16, (_Float16)r);   // f16 store
        }
    } else if (blk < 384) {
        // pack w_h[o][e] (= w_cell[o*1024 + 512 + e]) into f16: W2 as u16[o*512+e]
        const int base = (blk - 256) * 1024 + tid;
        #pragma unroll
        for (int i = 0; i < 4; ++i) {
            const int P = base + i * 256;          // 0..131071 (pairs)
            const int o = P >> 8, p = P & 255;
            h2_t v2;
            v2[0] = (_Float16)w_cell[(size_t)o * 1024 + 512 + 2 * p];
            v2[1] = (_Float16)w_cell[(size_t)o * 1024 + 512 + 2 * p + 1];
            W2[P] = __builtin_bit_cast(unsigned, v2);
        }
    } else {
        const int base = (blk - 384) * 2048 + tid;
        #pragma unroll
        for (int i = 0; i < 8; ++i) {
            const int idx = base + i * 256;        // 0..131071
            wh16[idx] = __builtin_bit_cast(u16, (_Float16)w_head[idx]);
        }
    }
}

// ---------------------------------------------------------------------------
// Recurrence, transposed MFMA: h_new^T[512 x 16] = w_h x h^T per step.
// MEASURED BEST (R12: 2541 us rnn_rec / 2697 us total): 4 blocks x 512
// threads, 12 AGPR k-slabs + 4 in-loop LDS k-slabs, f16 xw dbuf,
// token-2-ahead, bf/al register windows, cheap tanh (rcp), acc-pair
// phase split, LDS-only barrier. LDS = 128 + 32 = 160 KB.
// Measured-out (do NOT retry): 13/16 AGPR slabs (R1/R6: +14%/+74%),
// 16-wave TLP (R5: 2x), 8-CU row-split (R3: 4x), al-hoist (R9: +92%),
// asm MFMA (R7: wrong), setprio (R13: 3.6x), unroll x2 (R14: +14%),
// exp2 tanh (R13). Wins kept: f16 xw (R2), rcp tanh (R8), phase split.
// ---------------------------------------------------------------------------
__global__ __launch_bounds__(512, 2) void rnn_rec(
    const int* __restrict__ x, const float* __restrict__ h0,
    const u16* __restrict__ whf, const u16* __restrict__ embf,
    u16* __restrict__ hs)
{
    extern __shared__ __align__(16) u16 smem[];
    u16* wlds = smem;            // 65536 u16 = 128 KB: frag f=(sp*32+I)*64+lane
    u16* hbuf = smem + 65536;    // [2][8192] u16 = 32 KB, B-frag order

    const int tid  = threadIdx.x;
    const int wave = tid >> 6, lane = tid & 63;
    const int n    = lane & 15, quad = lane >> 4;   // n = batch-in-block
    const int b0   = blockIdx.x * 16;

    // ---- stage w_h k-slabs 12..15 into LDS (one-time, constant) ----
    #pragma unroll
    for (int g = 0; g < 16; ++g) {
        const int f = g * 512 + tid;                // frag id 0..8191
        const int lf = f & 63, If = (f >> 6) & 31, sp = f >> 11;
        const int m = If * 16 + (lf & 15);
        const int k = 384 + sp * 32 + (lf >> 4) * 8;
        *(uint4*)&wlds[(size_t)f * 8] = *(const uint4*)&whf[(size_t)m * 512 + k];
    }

    {   // h0 -> buffer 0, all 16 batch columns (B-frag order)
        const u16 u = __builtin_bit_cast(u16, (_Float16)h0[tid]);
        const int e = tid;
        const int ob = ((e >> 5) * 64 + ((e >> 3) & 3) * 16) * 8 + (e & 7);
        #pragma unroll
        for (int nn = 0; nn < 16; ++nn) hbuf[ob + nn * 8] = u;
    }

    // ---- resident A fragments: rows m = (wave*4+i)*16+n, k-slabs 0..11 ----
    h8_t Af[4][12];
    #pragma unroll
    for (int i = 0; i < 4; ++i)
        #pragma unroll
        for (int s = 0; s < 12; ++s)
            Af[i][s] = *(const h8_t*)&whf[(size_t)(((wave << 2) + i) * 16 + n) * EMB
                                          + s * 32 + quad * 8];

    const int* xp  = x  + (size_t)(b0 + n) * NT;
    u16*       hsp = hs + (size_t)(b0 + n) * NT * EMB;

    int eofs[4], wofs[4];
    #pragma unroll
    for (int i = 0; i < 4; ++i) {
        const int I = (wave << 2) + i;
        eofs[i] = I * 16 + (quad << 2);                       // e-offset of acc[i]
        const int qq = (2 * I + (quad >> 1)) & 3;
        wofs[i] = ((I >> 1) * 64 + qq * 16 + n) * 8 + (quad & 1) * 4;
    }

    __syncthreads();

    int vB = xp[0];
    h4_t xw_cur[4];                                           // f16 xw (2 regs each)
    #pragma unroll
    for (int i = 0; i < 4; ++i)
        xw_cur[i] = *(const h4_t*)&embf[(size_t)vB * EMB + eofs[i]];
    vB = xp[1];

    #pragma unroll 1
    for (int t = 0; t < NT; ++t) {
        const int vC = xp[(t + 2 < NT) ? t + 2 : NT - 1];     // token t+2 (clamped)
        h4_t xw_next[4];                                      // xw for t+1, in flight
        #pragma unroll
        for (int i = 0; i < 4; ++i)
            xw_next[i] = *(const h4_t*)&embf[(size_t)vB * EMB + eofs[i]];

        const u16* hb = &hbuf[(t & 1) * 8192];

        // ---- register windows: issue ALL step-t ds_reads up front ----
        h8_t bf[16];                                          // 64 VGPR
        #pragma unroll
        for (int s = 0; s < 16; ++s)
            bf[s] = *(const h8_t*)&hb[s * 512 + lane * 8];
        h8_t al[4][4];                                        // 64 VGPR
        #pragma unroll
        for (int sp = 0; sp < 4; ++sp)
            #pragma unroll
            for (int i = 0; i < 4; ++i)
                al[sp][i] = *(const h8_t*)
                    &wlds[((sp * 32 + (wave << 2) + i) * 64 + lane) * 8];

        f4_t acc[4];
        #pragma unroll
        for (int i = 0; i < 4; ++i) {                         // xw as C-init (cvt)
            acc[i][0] = (float)xw_cur[i][0];
            acc[i][1] = (float)xw_cur[i][1];
            acc[i][2] = (float)xw_cur[i][2];
            acc[i][3] = (float)xw_cur[i][3];
        }

        u16* hw = &hbuf[((t + 1) & 1) * 8192];

        // ================= PAIR 0: acc[0], acc[1] =================
        #pragma unroll
        for (int s = 0; s < 12; ++s) {
            acc[0] = __builtin_amdgcn_mfma_f32_16x16x32_f16(Af[0][s], bf[s],
                                                            acc[0], 0, 0, 0);
            acc[1] = __builtin_amdgcn_mfma_f32_16x16x32_f16(Af[1][s], bf[s],
                                                            acc[1], 0, 0, 0);
        }
        #pragma unroll
        for (int sp = 0; sp < 4; ++sp) {
            acc[0] = __builtin_amdgcn_mfma_f32_16x16x32_f16(al[sp][0], bf[12 + sp],
                                                            acc[0], 0, 0, 0);
            acc[1] = __builtin_amdgcn_mfma_f32_16x16x32_f16(al[sp][1], bf[12 + sp],
                                                            acc[1], 0, 0, 0);
        }
        // pair-0 tail: tanh + LDS + global write (overlaps pair-1 MFMAs below)
        #pragma unroll
        for (int i = 0; i < 2; ++i) {
            const f4_t a = acc[i];
            uint2 pk;
            pk.x = pk2(fast_tanh(a[0]), fast_tanh(a[1]));
            pk.y = pk2(fast_tanh(a[2]), fast_tanh(a[3]));
            *(uint2*)&hw[wofs[i]] = pk;                       // LDS, B-frag order
            *(uint2*)&hsp[(size_t)t * EMB + eofs[i]] = pk;    // global, no drain
        }

        // ================= PAIR 1: acc[2], acc[3] =================
        #pragma unroll
        for (int s = 0; s < 12; ++s) {
            acc[2] = __builtin_amdgcn_mfma_f32_16x16x32_f16(Af[2][s], bf[s],
                                                            acc[2], 0, 0, 0);
            acc[3] = __builtin_amdgcn_mfma_f32_16x16x32_f16(Af[3][s], bf[s],
                                                            acc[3], 0, 0, 0);
        }
        #pragma unroll
        for (int sp = 0; sp < 4; ++sp) {
            acc[2] = __builtin_amdgcn_mfma_f32_16x16x32_f16(al[sp][2], bf[12 + sp],
                                                            acc[2], 0, 0, 0);
            acc[3] = __builtin_amdgcn_mfma_f32_16x16x32_f16(al[sp][3], bf[12 + sp],
                                                            acc[3], 0, 0, 0);
        }
        #pragma unroll
        for (int i = 2; i < 4; ++i) {
            const f4_t a = acc[i];
            uint2 pk;
            pk.x = pk2(fast_tanh(a[0]), fast_tanh(a[1]));
            pk.y = pk2(fast_tanh(a[2]), fast_tanh(a[3]));
            *(uint2*)&hw[wofs[i]] = pk;                       // LDS, B-frag order
            *(uint2*)&hsp[(size_t)t * EMB + eofs[i]] = pk;    // global, no drain
        }

        vB = vC;
        #pragma unroll
        for (int i = 0; i < 4; ++i) xw_cur[i] = xw_next[i];

        // LDS-only barrier: NO vmcnt drain (hs stores / embf gathers fly on)
        asm volatile("s_waitcnt lgkmcnt(0)\n\ts_barrier" ::: "memory");
    }
}

// ---------------------------------------------------------------------------
// Head: out[bt][n] = hs[bt][:] @ w_head[n][:]^T + b_head[n], MFMA f16 16x16x32.
// ---------------------------------------------------------------------------
__global__ __launch_bounds__(512, 2) void head_kernel(
    const u16* __restrict__ hs, const u16* __restrict__ wh16,
    const float* __restrict__ b_head, float* __restrict__ out)
{
    const int tid  = threadIdx.x;
    const int wave = tid >> 6, lane = tid & 63;
    const int l15  = lane & 15, q = lane >> 4;
    const int bt0  = blockIdx.x * 64;

    __shared__ __align__(16) u16 As[64][520];   // +8 halfs pad: breaks bank aliasing

    {   // stage 64x512 f16 tile
        const uint4* src = (const uint4*)(hs + (size_t)bt0 * EMB);
        #pragma unroll
        for (int i = 0; i < 8; ++i) {
            const int idx = tid + i * 512;       // 0..4095 uint4s
            const int row = idx >> 6, col8 = idx & 63;
            *(uint4*)&As[row][col8 * 8] = src[idx];
        }
    }

    // B fragments: wave owns n-tiles {2*wave, 2*wave+1}; B[k][n] = w_head[n][k]
    uint4 bn[16][2];
    #pragma unroll
    for (int i = 0; i < 16; ++i)
        #pragma unroll
        for (int j = 0; j < 2; ++j) {
            const int n = wave * 32 + j * 16 + l15;
            const int k = i * 32 + q * 8;
            bn[i][j] = *(const uint4*)(wh16 + (size_t)n * EMB + k);
        }
    __syncthreads();

    #pragma unroll 1
    for (int mt = 0; mt < 4; ++mt) {
        f4_t acc0 = {0.f, 0.f, 0.f, 0.f}, acc1 = {0.f, 0.f, 0.f, 0.f};
        const int row = mt * 16 + l15;
        #pragma unroll
        for (int i = 0; i < 16; ++i) {
            const int k = i * 32 + q * 8;
            h8_t a = *(const h8_t*)&As[row][k];
            acc0 = __builtin_amdgcn_mfma_f32_16x16x32_f16(
                a, __builtin_bit_cast(h8_t, bn[i][0]), acc0, 0, 0, 0);
            acc1 = __builtin_amdgcn_mfma_f32_16x16x32_f16(
                a, __builtin_bit_cast(h8_t, bn[i][1]), acc1, 0, 0, 0);
        }
        #pragma unroll
        for (int j = 0; j < 2; ++j) {
            const int n = wave * 32 + j * 16 + l15;
            const float bh = b_head[n];
            const f4_t av = j ? acc1 : acc0;
            #pragma unroll
            for (int r = 0; r < 4; ++r) {
                const int orow = bt0 + mt * 16 + q * 4 + r;   // D: row=q*4+r, col=l15
                out[(size_t)orow * VOCAB + n] = av[r] + bh;
            }
        }
    }
}

extern "C" void kernel_launch(void* const* d_in, const int* in_sizes, int n_in,
                              void* d_out, int out_size, void* d_ws, size_t ws_size,
                              hipStream_t stream) {
    (void)in_sizes; (void)n_in; (void)out_size; (void)ws_size;
    const int*   x      = (const int*)  d_in[0];
    const float* emb    = (const float*)d_in[1];
    const float* w_cell = (const float*)d_in[2];
    const float* b_cell = (const float*)d_in[3];
    const float* w_head = (const float*)d_in[4];
    const float* b_head = (const float*)d_in[5];
    const float* h0     = (const float*)d_in[6];
    float* out = (float*)d_out;

    char* ws = (char*)d_ws;
    u16*      embf = (u16*)     (ws);                 // 256*512*2 = 256 KB (f16)
    unsigned* W2   = (unsigned*)(ws + 524288);        // 512*256*4 = 512 KB (f16 w_h)
    u16*      wh16 = (u16*)     (ws + 1048576);       // 256*512*2 = 256 KB
    u16*      hs   = (u16*)     (ws + 1310720);       // 64*1024*512*2 = 64 MB

    // allow 160 KB dynamic LDS (idempotent; same every call -> graph-safe)
    hipFuncSetAttribute((const void*)rnn_rec,
                        hipFuncAttributeMaxDynamicSharedMemorySize, 163840);

    prep_kernel<<<dim3(448), dim3(256), 0, stream>>>(emb, w_cell, b_cell, w_head,
                                                     embf, W2, wh16);
    rnn_rec<<<dim3(4), dim3(512), 163840, stream>>>(x, h0, (const u16*)W2, embf, hs);
    head_kernel<<<dim3((NB * NT) / 64), dim3(512), 0, stream>>>(hs, wh16, b_head, out);
}